// Round 1
// baseline (15828.046 us; speedup 1.0000x reference)
//
#include <hip/hip_runtime.h>

typedef unsigned short u16;
typedef unsigned int u32;
typedef __attribute__((ext_vector_type(8))) short bf16x8;   // 8 x bf16 (4 VGPRs)
typedef __attribute__((ext_vector_type(4))) float f32x4;

#define NHID 850
#define BATCH 256
#define TSTEPS 128
#define KPAD 896      // padded K for states / x region (14 k-tiles of 64)
#define KPAD0 1792    // L0: x region [0,896) + h region [896,1792)

#define ACT_SIG 0
#define ACT_TANH 1
#define ACT_RELU 2
#define ACT_ID 3

__device__ __forceinline__ u16 f2bf(float f) {
  u32 u = __float_as_uint(f);
  u32 r = (u + 0x7fffu + ((u >> 16) & 1u)) >> 16;   // RNE
  return (u16)r;
}
__device__ __forceinline__ float sigm(float x) { return 1.f / (1.f + __expf(-x)); }
__device__ __forceinline__ float act_apply(float x, int a) {
  if (a == ACT_SIG) return sigm(x);
  if (a == ACT_TANH) return 2.f * sigm(2.f * x) - 1.f;  // NaN-safe tanh
  if (a == ACT_RELU) return fmaxf(x, 0.f);
  return x;
}

#define GLOAD_LDS16(gsrc, ldst)                                                     \
  __builtin_amdgcn_global_load_lds((const __attribute__((address_space(1))) void*)(gsrc), \
                                   (__attribute__((address_space(3))) void*)(ldst), 16, 0, 0)

// ---------------------------------------------------------------- utility
__global__ void zero_kernel(uint4* p, u32 n) {
  u32 i = blockIdx.x * blockDim.x + threadIdx.x;
  const u32 stride = gridDim.x * blockDim.x;
  const uint4 z = {0u, 0u, 0u, 0u};
  for (; i < n; i += stride) p[i] = z;
}

// x (T,B,850) fp32 -> bf16 padded [T*B][896]; hidden (B,850) -> hb [B][896]
__global__ void convert_kernel(const float* __restrict__ x, const float* __restrict__ h0,
                               u16* __restrict__ xb, u16* __restrict__ hb) {
  const u32 NX = (u32)TSTEPS * BATCH * NHID;
  u32 i = blockIdx.x * blockDim.x + threadIdx.x;
  if (i < NX) {
    const u32 tb = i / NHID, j = i - tb * NHID;
    xb[(size_t)tb * KPAD + j] = f2bf(x[i]);
  } else if (i < NX + (u32)BATCH * NHID) {
    const u32 k = i - NX;
    const u32 b = k / NHID, j = k - b * NHID;
    hb[(size_t)b * KPAD + j] = f2bf(h0[k]);
  }
}

// ---------------------------------------------------------------- precompute (fp32)
// W0comb[m][n] = sum_r U[m][r]*sig[r]*V[r][n];  stored transposed+split+padded:
//   n<850:  outC[n*KPAD0 + rp(m)]   else outH[(n-850)*KPAD0 + rp(m)],  rp(m)=m<850?m:m+46
__global__ __launch_bounds__(256) void prew0_kernel(const float* __restrict__ U,
                                                    const float* __restrict__ sig,
                                                    const float* __restrict__ V,
                                                    u16* __restrict__ outC,
                                                    u16* __restrict__ outH) {
  const int M = 1700, N = 1700, K = 1700;
  __shared__ float sA[64][17];
  __shared__ float sB[16][65];
  const int tid = threadIdx.x;
  const int tx = tid & 15, ty = tid >> 4;
  const int m0 = blockIdx.x * 64, n0 = blockIdx.y * 64;
  float acc[4][4] = {};
  for (int kb = 0; kb < K; kb += 16) {
#pragma unroll
    for (int i = 0; i < 4; ++i) {
      const int e = tid + i * 256;
      const int r = e >> 4, c = e & 15;
      const int mm = m0 + r, kk = kb + c;
      sA[r][c] = (mm < M && kk < K) ? U[(size_t)mm * K + kk] * sig[kk] : 0.f;
    }
#pragma unroll
    for (int i = 0; i < 4; ++i) {
      const int e = tid + i * 256;
      const int r = e >> 6, c = e & 63;
      const int kk = kb + r, nn = n0 + c;
      sB[r][c] = (kk < K && nn < N) ? V[(size_t)kk * N + nn] : 0.f;
    }
    __syncthreads();
#pragma unroll
    for (int k = 0; k < 16; ++k) {
      float a[4], b[4];
#pragma unroll
      for (int i = 0; i < 4; ++i) a[i] = sA[tx * 4 + i][k];
#pragma unroll
      for (int j = 0; j < 4; ++j) b[j] = sB[k][ty * 4 + j];
#pragma unroll
      for (int i = 0; i < 4; ++i)
#pragma unroll
        for (int j = 0; j < 4; ++j) acc[i][j] += a[i] * b[j];
    }
    __syncthreads();
  }
#pragma unroll
  for (int i = 0; i < 4; ++i) {
    const int m = m0 + tx * 4 + i;
    if (m >= M) continue;
    const int rp = (m < 850) ? m : m + 46;
#pragma unroll
    for (int j = 0; j < 4; ++j) {
      const int n = n0 + ty * 4 + j;
      if (n >= N) continue;
      if (n < 850) outC[(size_t)n * KPAD0 + rp] = f2bf(acc[i][j]);
      else outH[(size_t)(n - 850) * KPAD0 + rp] = f2bf(acc[i][j]);
    }
  }
}

// per node i: Wcomb[m][n] = sum_r U_i[m][r]*sig_i[r]*V_i[r][n]  (m,r<850, n<1700, V rows 0..849)
__global__ __launch_bounds__(256) void prewn_kernel(const float* __restrict__ Uall,
                                                    const float* __restrict__ sigall,
                                                    const float* __restrict__ Vall,
                                                    u16* __restrict__ outBase) {
  const int M = 850, N = 1700, K = 850;
  const int ndi = blockIdx.z;
  const float* U = Uall + (size_t)ndi * 850 * 850;
  const float* sig = sigall + (size_t)ndi * 850;
  const float* V = Vall + (size_t)ndi * 1700 * 1700;
  u16* outC = outBase + (size_t)ndi * 2 * KPAD * KPAD;
  u16* outH = outC + (size_t)KPAD * KPAD;
  __shared__ float sA[64][17];
  __shared__ float sB[16][65];
  const int tid = threadIdx.x;
  const int tx = tid & 15, ty = tid >> 4;
  const int m0 = blockIdx.x * 64, n0 = blockIdx.y * 64;
  float acc[4][4] = {};
  for (int kb = 0; kb < K; kb += 16) {
#pragma unroll
    for (int i = 0; i < 4; ++i) {
      const int e = tid + i * 256;
      const int r = e >> 4, c = e & 15;
      const int mm = m0 + r, kk = kb + c;
      sA[r][c] = (mm < M && kk < K) ? U[(size_t)mm * K + kk] * sig[kk] : 0.f;
    }
#pragma unroll
    for (int i = 0; i < 4; ++i) {
      const int e = tid + i * 256;
      const int r = e >> 6, c = e & 63;
      const int kk = kb + r, nn = n0 + c;
      sB[r][c] = (kk < K && nn < N) ? V[(size_t)kk * 1700 + nn] : 0.f;
    }
    __syncthreads();
#pragma unroll
    for (int k = 0; k < 16; ++k) {
      float a[4], b[4];
#pragma unroll
      for (int i = 0; i < 4; ++i) a[i] = sA[tx * 4 + i][k];
#pragma unroll
      for (int j = 0; j < 4; ++j) b[j] = sB[k][ty * 4 + j];
#pragma unroll
      for (int i = 0; i < 4; ++i)
#pragma unroll
        for (int j = 0; j < 4; ++j) acc[i][j] += a[i] * b[j];
    }
    __syncthreads();
  }
#pragma unroll
  for (int i = 0; i < 4; ++i) {
    const int m = m0 + tx * 4 + i;
    if (m >= M) continue;
#pragma unroll
    for (int j = 0; j < 4; ++j) {
      const int n = n0 + ty * 4 + j;
      if (n >= N) continue;
      if (n < 850) outC[(size_t)n * KPAD + m] = f2bf(acc[i][j]);
      else outH[(size_t)(n - 850) * KPAD + m] = f2bf(acc[i][j]);
    }
  }
}

// ---------------------------------------------------------------- main stage GEMM
struct NodeDesc {
  const u16* A;      // bf16 [256][KPAD]
  const u16* A2;     // second region (L0 only) or nullptr
  const u16* Bc;     // weights, transposed [n][k], c-half
  const u16* Bh;     // h-half
  const float* sp;   // predecessor state fp32 [256][850]
  float* outF;       // new state fp32
  u16* outB;         // new state bf16 [256][KPAD]
  int act;
};
struct StageArgs {
  NodeDesc d[3];
  int Kt, ktA, bStride;
};

__global__ __launch_bounds__(256) void stage_kernel(StageArgs sa) {
  const NodeDesc nd = sa.d[blockIdx.z];
  __shared__ __align__(16) u16 lA[2][4096];
  __shared__ __align__(16) u16 lBc[2][4096];
  __shared__ __align__(16) u16 lBh[2][4096];
  const int tid = threadIdx.x;
  const int lane = tid & 63;
  const int w = tid >> 6;
  const int wm = (w & 1) * 32;
  const int wn = (w >> 1) * 32;
  const int m0 = blockIdx.x * 64;
  const int n0 = blockIdx.y * 64;

  f32x4 acc[2][2][2] = {};   // [half][mf][nf]

  auto stage = [&](int buf, int kt) {
    const u16* Asrc;
    int ktl;
    if (kt < sa.ktA) { Asrc = nd.A; ktl = kt; }
    else { Asrc = nd.A2; ktl = kt - sa.ktA; }
#pragma unroll
    for (int r2 = 0; r2 < 2; ++r2) {
      const int e = tid + 256 * r2;
      const int row = e >> 3;
      const int q = (e & 7) ^ (row & 7);          // XOR-swizzled source chunk
      const u16* gA = Asrc + (size_t)(m0 + row) * KPAD + ktl * 64 + q * 8;
      GLOAD_LDS16(gA, &lA[buf][e * 8]);
      const u16* gBc = nd.Bc + (size_t)(n0 + row) * sa.bStride + kt * 64 + q * 8;
      GLOAD_LDS16(gBc, &lBc[buf][e * 8]);
      const u16* gBh = nd.Bh + (size_t)(n0 + row) * sa.bStride + kt * 64 + q * 8;
      GLOAD_LDS16(gBh, &lBh[buf][e * 8]);
    }
  };

  stage(0, 0);
  int cur = 0;
  for (int kt = 0; kt < sa.Kt; ++kt) {
    __syncthreads();                       // drains vmcnt: buf[cur] staged, buffers free
    if (kt + 1 < sa.Kt) stage(cur ^ 1, kt + 1);   // overlap next loads with compute
#pragma unroll
    for (int ks = 0; ks < 2; ++ks) {
      const int kg = lane >> 4;
      bf16x8 af[2], bc[2], bh[2];
#pragma unroll
      for (int mf = 0; mf < 2; ++mf) {
        const int row = wm + mf * 16 + (lane & 15);
        const int p = (ks * 4 + kg) ^ (row & 7);
        af[mf] = *(const bf16x8*)&lA[cur][row * 64 + p * 8];
      }
#pragma unroll
      for (int nf = 0; nf < 2; ++nf) {
        const int nr = wn + nf * 16 + (lane & 15);
        const int p = (ks * 4 + kg) ^ (nr & 7);
        bc[nf] = *(const bf16x8*)&lBc[cur][nr * 64 + p * 8];
        bh[nf] = *(const bf16x8*)&lBh[cur][nr * 64 + p * 8];
      }
#pragma unroll
      for (int mf = 0; mf < 2; ++mf)
#pragma unroll
        for (int nf = 0; nf < 2; ++nf) {
          acc[0][mf][nf] = __builtin_amdgcn_mfma_f32_16x16x32_bf16(af[mf], bc[nf], acc[0][mf][nf], 0, 0, 0);
          acc[1][mf][nf] = __builtin_amdgcn_mfma_f32_16x16x32_bf16(af[mf], bh[nf], acc[1][mf][nf], 0, 0, 0);
        }
    }
    cur ^= 1;
  }

  // epilogue: C/D layout col=lane&15, row=(lane>>4)*4+reg  [m89]
  const int colb = n0 + wn + (lane & 15);
  const int rowb = m0 + wm + ((lane >> 4) << 2);
#pragma unroll
  for (int nf = 0; nf < 2; ++nf) {
    const int j = colb + nf * 16;
    if (j >= NHID) continue;
#pragma unroll
    for (int mf = 0; mf < 2; ++mf) {
      const int mb = rowb + mf * 16;
      const f32x4 ac = acc[0][mf][nf];
      const f32x4 ah = acc[1][mf][nf];
#pragma unroll
      for (int r = 0; r < 4; ++r) {
        const int m = mb + r;
        const float c = sigm(ac[r]);
        const float hv = act_apply(ah[r], nd.act);
        const float spv = nd.sp[m * NHID + j];
        const float s = spv + c * (hv - spv);
        nd.outF[m * NHID + j] = s;
        nd.outB[(size_t)m * KPAD + j] = f2bf(s);
      }
    }
  }
}

// ---------------------------------------------------------------- final stage: nodes 5,7 + mean
struct FinalArgs {
  const u16* A;        // s5 bf16
  const u16* B[4];     // W5c, W5h, W7c, W7h
  const float* s1; const float* s2; const float* s3;
  const float* s4; const float* s5; const float* s7;
  float* outH;         // d_out + t*B*NHID
  u16* hb;             // h bf16 for next step
};

__global__ __launch_bounds__(256) void final_kernel(FinalArgs fa) {
  __shared__ __align__(16) u16 lA[2][4096];
  __shared__ __align__(16) u16 lB[2][4][4096];
  const int tid = threadIdx.x;
  const int lane = tid & 63;
  const int w = tid >> 6;
  const int wm = (w & 1) * 32;
  const int wn = (w >> 1) * 32;
  const int m0 = blockIdx.x * 64;
  const int n0 = blockIdx.y * 64;

  f32x4 acc[4][2][2] = {};   // [5c,5h,7c,7h][mf][nf]

  auto stage = [&](int buf, int kt) {
#pragma unroll
    for (int r2 = 0; r2 < 2; ++r2) {
      const int e = tid + 256 * r2;
      const int row = e >> 3;
      const int q = (e & 7) ^ (row & 7);
      GLOAD_LDS16(fa.A + (size_t)(m0 + row) * KPAD + kt * 64 + q * 8, &lA[buf][e * 8]);
#pragma unroll
      for (int b = 0; b < 4; ++b)
        GLOAD_LDS16(fa.B[b] + (size_t)(n0 + row) * KPAD + kt * 64 + q * 8, &lB[buf][b][e * 8]);
    }
  };

  stage(0, 0);
  int cur = 0;
  for (int kt = 0; kt < 14; ++kt) {
    __syncthreads();
    if (kt + 1 < 14) stage(cur ^ 1, kt + 1);
#pragma unroll
    for (int ks = 0; ks < 2; ++ks) {
      const int kg = lane >> 4;
      bf16x8 af[2], bb[4][2];
#pragma unroll
      for (int mf = 0; mf < 2; ++mf) {
        const int row = wm + mf * 16 + (lane & 15);
        const int p = (ks * 4 + kg) ^ (row & 7);
        af[mf] = *(const bf16x8*)&lA[cur][row * 64 + p * 8];
      }
#pragma unroll
      for (int b = 0; b < 4; ++b)
#pragma unroll
        for (int nf = 0; nf < 2; ++nf) {
          const int nr = wn + nf * 16 + (lane & 15);
          const int p = (ks * 4 + kg) ^ (nr & 7);
          bb[b][nf] = *(const bf16x8*)&lB[cur][b][nr * 64 + p * 8];
        }
#pragma unroll
      for (int b = 0; b < 4; ++b)
#pragma unroll
        for (int mf = 0; mf < 2; ++mf)
#pragma unroll
          for (int nf = 0; nf < 2; ++nf)
            acc[b][mf][nf] = __builtin_amdgcn_mfma_f32_16x16x32_bf16(af[mf], bb[b][nf], acc[b][mf][nf], 0, 0, 0);
    }
    cur ^= 1;
  }

  const int colb = n0 + wn + (lane & 15);
  const int rowb = m0 + wm + ((lane >> 4) << 2);
#pragma unroll
  for (int nf = 0; nf < 2; ++nf) {
    const int j = colb + nf * 16;
    if (j >= NHID) continue;
#pragma unroll
    for (int mf = 0; mf < 2; ++mf) {
      const int mb = rowb + mf * 16;
#pragma unroll
      for (int r = 0; r < 4; ++r) {
        const int m = mb + r;
        const int idx = m * NHID + j;
        const float s5v = fa.s5[idx];
        const float c6 = sigm(acc[0][mf][nf][r]);
        const float h6 = sigm(acc[1][mf][nf][r]);     // node5 act = sigmoid
        const float s6 = s5v + c6 * (h6 - s5v);
        const float c8 = sigm(acc[2][mf][nf][r]);
        const float h8 = fmaxf(acc[3][mf][nf][r], 0.f); // node7 act = relu
        const float s8 = s5v + c8 * (h8 - s5v);
        const float sum = fa.s1[idx] + fa.s2[idx] + fa.s3[idx] + fa.s4[idx]
                        + s5v + fa.s7[idx] + s6 + s8;
        const float h = sum * 0.125f;
        fa.outH[idx] = h;
        fa.hb[(size_t)m * KPAD + j] = f2bf(h);
      }
    }
  }
}

// ---------------------------------------------------------------- host
extern "C" void kernel_launch(void* const* d_in, const int* in_sizes, int n_in,
                              void* d_out, int out_size, void* d_ws, size_t ws_size,
                              hipStream_t stream) {
  const float* x = (const float*)d_in[0];
  const float* h0 = (const float*)d_in[1];
  const float* W0U = (const float*)d_in[2];
  const float* W0s = (const float*)d_in[3];
  const float* W0V = (const float*)d_in[4];
  const float* WsU = (const float*)d_in[5];
  const float* Wss = (const float*)d_in[6];
  const float* WsV = (const float*)d_in[7];
  float* out = (float*)d_out;
  char* ws = (char*)d_ws;

  const size_t SZ_W0HALF = (size_t)KPAD * KPAD0 * 2;
  const size_t OFF_W0C = 0, OFF_W0H = SZ_W0HALF;
  const size_t OFF_WN = 2 * SZ_W0HALF;
  const size_t SZ_WNHALF = (size_t)KPAD * KPAD * 2;
  const size_t OFF_XB = OFF_WN + 16 * SZ_WNHALF;
  const size_t SZ_XB = (size_t)TSTEPS * BATCH * KPAD * 2;
  const size_t OFF_HB = OFF_XB + SZ_XB;
  const size_t SZ_HB = (size_t)BATCH * KPAD * 2;
  const size_t OFF_SF = OFF_HB + SZ_HB;
  const size_t SZ_SF = (size_t)BATCH * NHID * 4;
  const size_t OFF_SB = OFF_SF + 9 * SZ_SF;
  const size_t SZ_SB = (size_t)BATCH * KPAD * 2;
  const size_t TOTAL = OFF_SB + 9 * SZ_SB;   // ~103.3 MB

  u16* w0c = (u16*)(ws + OFF_W0C);
  u16* w0h = (u16*)(ws + OFF_W0H);
  u16* wnBase = (u16*)(ws + OFF_WN);
  u16* xb = (u16*)(ws + OFF_XB);
  u16* hb = (u16*)(ws + OFF_HB);

  const size_t zbytes = (TOTAL <= ws_size) ? TOTAL : ws_size;
  zero_kernel<<<2048, 256, 0, stream>>>((uint4*)ws, (u32)(zbytes / 16));
  const u32 convTotal = (u32)TSTEPS * BATCH * NHID + (u32)BATCH * NHID;
  convert_kernel<<<(convTotal + 255) / 256, 256, 0, stream>>>(x, h0, xb, hb);
  prew0_kernel<<<dim3(27, 27), 256, 0, stream>>>(W0U, W0s, W0V, w0c, w0h);
  prewn_kernel<<<dim3(14, 27, 8), 256, 0, stream>>>(WsU, Wss, WsV, wnBase);

  auto wnc = [&](int i) { return wnBase + (size_t)i * 2 * KPAD * KPAD; };
  auto wnh = [&](int i) { return wnBase + (size_t)i * 2 * KPAD * KPAD + (size_t)KPAD * KPAD; };
  auto sf = [&](int k) { return (float*)(ws + OFF_SF + (size_t)k * SZ_SF); };
  auto sb = [&](int k) { return (u16*)(ws + OFF_SB + (size_t)k * SZ_SB); };

  for (int t = 0; t < TSTEPS; ++t) {
    const float* hprev = (t == 0) ? h0 : (out + (size_t)(t - 1) * BATCH * NHID);
    {
      StageArgs a = {};
      a.d[0] = NodeDesc{ xb + (size_t)t * BATCH * KPAD, hb, w0c, w0h, hprev, sf(0), sb(0), ACT_TANH };
      a.Kt = 28; a.ktA = 14; a.bStride = KPAD0;
      stage_kernel<<<dim3(4, 14, 1), 256, 0, stream>>>(a);
    }
    {
      StageArgs a = {};
      a.d[0] = NodeDesc{ sb(0), nullptr, wnc(0), wnh(0), sf(0), sf(1), sb(1), ACT_SIG };
      a.Kt = 14; a.ktA = 14; a.bStride = KPAD;
      stage_kernel<<<dim3(4, 14, 1), 256, 0, stream>>>(a);
    }
    {
      StageArgs a = {};
      a.d[0] = NodeDesc{ sb(1), nullptr, wnc(1), wnh(1), sf(1), sf(2), sb(2), ACT_RELU };
      a.d[1] = NodeDesc{ sb(1), nullptr, wnc(2), wnh(2), sf(1), sf(3), sb(3), ACT_RELU };
      a.d[2] = NodeDesc{ sb(1), nullptr, wnc(3), wnh(3), sf(1), sf(4), sb(4), ACT_ID };
      a.Kt = 14; a.ktA = 14; a.bStride = KPAD;
      stage_kernel<<<dim3(4, 14, 3), 256, 0, stream>>>(a);
    }
    {
      StageArgs a = {};
      a.d[0] = NodeDesc{ sb(2), nullptr, wnc(4), wnh(4), sf(2), sf(5), sb(5), ACT_TANH };
      a.d[1] = NodeDesc{ sb(3), nullptr, wnc(6), wnh(6), sf(3), sf(7), sb(7), ACT_TANH };
      a.Kt = 14; a.ktA = 14; a.bStride = KPAD;
      stage_kernel<<<dim3(4, 14, 2), 256, 0, stream>>>(a);
    }
    {
      FinalArgs f;
      f.A = sb(5);
      f.B[0] = wnc(5); f.B[1] = wnh(5); f.B[2] = wnc(7); f.B[3] = wnh(7);
      f.s1 = sf(1); f.s2 = sf(2); f.s3 = sf(3); f.s4 = sf(4); f.s5 = sf(5); f.s7 = sf(7);
      f.outH = out + (size_t)t * BATCH * NHID;
      f.hb = hb;
      final_kernel<<<dim3(4, 14), 256, 0, stream>>>(f);
    }
  }
  hipMemcpyAsync(out + (size_t)TSTEPS * BATCH * NHID,
                 out + (size_t)(TSTEPS - 1) * BATCH * NHID,
                 (size_t)BATCH * NHID * sizeof(float), hipMemcpyDeviceToDevice, stream);
}